// Round 2
// baseline (4095.144 us; speedup 1.0000x reference)
//
#include <hip/hip_runtime.h>
#include <hip/hip_bf16.h>
#include <stdint.h>

#define D     128
#define DPAD  136   // padded LDS row stride (bf16 elems) -> 272B
#define TM    64    // rows (edges or nodes) per block tile

typedef __bf16 bf16_t;
typedef __bf16 bf16x8 __attribute__((ext_vector_type(8)));
typedef float  f32x4  __attribute__((ext_vector_type(4)));

// ---------------- preprocessing kernels ----------------

__global__ void deg_kernel(const int* __restrict__ ei, const int* __restrict__ et,
                           int E, int* __restrict__ cnt, int* __restrict__ rel_cnt, int R) {
    __shared__ int h[64];
    if (threadIdx.x < R) h[threadIdx.x] = 0;
    __syncthreads();
    int e = blockIdx.x * blockDim.x + threadIdx.x;
    if (e < E) {
        atomicAdd(&cnt[ei[E + e]], 1);      // dst in-degree
        atomicAdd(&h[et[e]], 1);            // LDS relation histogram
    }
    __syncthreads();
    if (threadIdx.x < R && h[threadIdx.x]) atomicAdd(&rel_cnt[threadIdx.x], h[threadIdx.x]);
}

__global__ void inv_kernel(const int* __restrict__ cnt, float* __restrict__ inv, int N) {
    int n = blockIdx.x * blockDim.x + threadIdx.x;
    if (n < N) inv[n] = 1.0f / (float)max(cnt[n], 1);
}

__global__ void prefix_kernel(const int* __restrict__ rel_cnt, int R,
                              int* __restrict__ rel_off, int* __restrict__ rel_ptr,
                              int* __restrict__ tile_base,
                              int* __restrict__ tile_rel, int* __restrict__ tile_idx) {
    __shared__ int s_off[65], s_tb[65];
    if (threadIdx.x == 0) {
        int acc = 0, tb = 0;
        for (int r = 0; r < R; r++) {
            s_off[r] = acc; s_tb[r] = tb;
            acc += rel_cnt[r];
            tb  += (rel_cnt[r] + TM - 1) / TM;
        }
        s_off[R] = acc; s_tb[R] = tb;
    }
    __syncthreads();
    if (threadIdx.x <= R) {
        rel_off[threadIdx.x]   = s_off[threadIdx.x];
        tile_base[threadIdx.x] = s_tb[threadIdx.x];
        if (threadIdx.x < R) rel_ptr[threadIdx.x] = s_off[threadIdx.x];
    }
    for (int r = 0; r < R; r++) {
        int nt = s_tb[r + 1] - s_tb[r];
        for (int t = threadIdx.x; t < nt; t += blockDim.x) {
            tile_rel[s_tb[r] + t] = r;
            tile_idx[s_tb[r] + t] = t;
        }
    }
}

// counting-sort scatter, wave-aggregated atomics
__global__ void scatter_kernel(const int* __restrict__ ei, const int* __restrict__ et,
                               int E, int R, int* __restrict__ rel_ptr,
                               int* __restrict__ s_src, int* __restrict__ s_dst) {
    int e = blockIdx.x * blockDim.x + threadIdx.x;
    int lane = threadIdx.x & 63;
    int myr = (e < E) ? et[e] : -1;
    unsigned long long below = (1ull << lane) - 1ull;
    int p = 0;
    for (int r = 0; r < R; r++) {
        unsigned long long mask = __ballot(myr == r);
        if (!mask) continue;
        int leader = __builtin_ctzll(mask);
        int base = 0;
        if (lane == leader) base = atomicAdd(&rel_ptr[r], __popcll(mask));
        base = __shfl(base, leader, 64);
        if (myr == r) p = base + (int)__popcll(mask & below);
    }
    if (e < E) { s_src[p] = ei[e]; s_dst[p] = ei[E + e]; }
}

// transpose+convert all weight matrices once: Wt[m][o][d] = (bf16)W[m][d][o]
__global__ void transpose_kernel(const float* __restrict__ W1, const float* __restrict__ root1,
                                 const float* __restrict__ W2, const float* __restrict__ root2,
                                 int R, bf16_t* __restrict__ Wt) {
    int m = blockIdx.x;  // 0..2R+1
    const float* src;
    if (m < R)            src = W1 + (size_t)m * D * D;
    else if (m < 2 * R)   src = W2 + (size_t)(m - R) * D * D;
    else if (m == 2 * R)  src = root1;
    else                  src = root2;
    bf16_t* dstp = Wt + (size_t)m * D * D;
    for (int i = threadIdx.x; i < D * D; i += blockDim.x) {
        int o = i >> 7, d = i & 127;
        dstp[i] = (bf16_t)src[d * D + o];
    }
}

// x_bf16[n][:] = (bf16)emb[entity[n]][:]  -- one thread per 8 elements
__global__ void gather_kernel(const int* __restrict__ entity, const float* __restrict__ emb,
                              bf16_t* __restrict__ x, int N) {
    int t = blockIdx.x * blockDim.x + threadIdx.x;
    if (t >= N * 16) return;
    int n = t >> 4, c = t & 15;
    const float4* src = (const float4*)(emb + (size_t)entity[n] * D) + c * 2;
    float4 a = src[0], b = src[1];
    bf16x8 v = { (bf16_t)a.x, (bf16_t)a.y, (bf16_t)a.z, (bf16_t)a.w,
                 (bf16_t)b.x, (bf16_t)b.y, (bf16_t)b.z, (bf16_t)b.w };
    *(bf16x8*)(x + (size_t)t * 8) = v;
}

// ---------------- main GEMM kernels ----------------

// per-tile: 64 edges of one relation. msg = x[src] @ W[r]; agg[dst] += msg * inv_cnt[dst]
__global__ __launch_bounds__(256, 3)
void edge_gemm(const bf16_t* __restrict__ x, const bf16_t* __restrict__ Wt,
               const int* __restrict__ s_src_g, const int* __restrict__ s_dst_g,
               const float* __restrict__ inv_cnt,
               const int* __restrict__ rel_off, const int* __restrict__ tile_base,
               const int* __restrict__ tile_rel, const int* __restrict__ tile_idx,
               int R, float* __restrict__ agg) {
    __shared__ bf16_t sW[D * DPAD];
    __shared__ bf16_t sA[TM * DPAD];
    __shared__ int   sh_src[TM];
    __shared__ int   sh_dst[TM];
    __shared__ float sh_inv[TM];

    int tile = blockIdx.x;
    if (tile >= tile_base[R]) return;
    int r = tile_rel[tile];
    int t = tile_idx[tile];
    int base = rel_off[r] + t * TM;
    int cntE = min(TM, rel_off[r + 1] - base);

    int tid = threadIdx.x;
    if (tid < TM) {
        int ok = tid < cntE;
        int s  = ok ? s_src_g[base + tid] : 0;
        int dd = ok ? s_dst_g[base + tid] : 0;
        sh_src[tid] = s;
        sh_dst[tid] = dd;
        sh_inv[tid] = ok ? inv_cnt[dd] : 0.f;
    }
    // stage W^T (L2-hot: only R distinct 32KB matrices)
    const uint4* Wg = (const uint4*)(Wt + (size_t)r * D * D);
    for (int c = tid; c < D * 16; c += 256) {
        int row = c >> 4, col = c & 15;
        *(uint4*)&sW[row * DPAD + col * 8] = Wg[c];
    }
    __syncthreads();
    // gather A rows (256B each, random from 25.6MB x)
    for (int c = tid; c < TM * 16; c += 256) {
        int row = c >> 4, col = c & 15;
        const uint4* xr = (const uint4*)(x + (size_t)sh_src[row] * D);
        *(uint4*)&sA[row * DPAD + col * 8] = xr[col];
    }
    __syncthreads();

    int lane = tid & 63;
    int w = tid >> 6;            // wave -> output cols [w*32, w*32+32)
    int m = lane & 15, q = lane >> 4;
    f32x4 acc[4][2];
#pragma unroll
    for (int a = 0; a < 4; a++)
#pragma unroll
        for (int b = 0; b < 2; b++) acc[a][b] = (f32x4){0.f, 0.f, 0.f, 0.f};

#pragma unroll
    for (int k0 = 0; k0 < D; k0 += 32) {
        bf16x8 af[4], bfr[2];
#pragma unroll
        for (int mt = 0; mt < 4; mt++)
            af[mt] = *(const bf16x8*)&sA[(mt * 16 + m) * DPAD + k0 + q * 8];
#pragma unroll
        for (int nt = 0; nt < 2; nt++)
            bfr[nt] = *(const bf16x8*)&sW[(w * 32 + nt * 16 + m) * DPAD + k0 + q * 8];
#pragma unroll
        for (int mt = 0; mt < 4; mt++)
#pragma unroll
            for (int nt = 0; nt < 2; nt++)
                acc[mt][nt] = __builtin_amdgcn_mfma_f32_16x16x32_bf16(af[mt], bfr[nt], acc[mt][nt], 0, 0, 0);
    }

    // epilogue: scale by 1/deg and atomic-accumulate (C layout: col=lane&15, row=q*4+i)
#pragma unroll
    for (int mt = 0; mt < 4; mt++) {
#pragma unroll
        for (int i = 0; i < 4; i++) {
            int edge = mt * 16 + q * 4 + i;
            if (edge < cntE) {
                float sc = sh_inv[edge];
                float* ag = agg + (size_t)sh_dst[edge] * D;
#pragma unroll
                for (int nt = 0; nt < 2; nt++) {
                    int o = w * 32 + nt * 16 + m;
                    atomicAdd(&ag[o], acc[mt][nt][i] * sc);
                }
            }
        }
    }
}

// out[n] = (relu?)( x[n] @ root + agg[n] ).  If out16 != null write bf16 (in-place
// on x is safe: each block reads only its own 64 rows before writing them),
// else write fp32 to out32.
__global__ __launch_bounds__(256, 3)
void root_gemm(const bf16_t* x, const bf16_t* __restrict__ roott,
               const float* __restrict__ agg, bf16_t* out16, float* out32,
               int N, int relu) {
    __shared__ bf16_t sW[D * DPAD];
    __shared__ bf16_t sA[TM * DPAD];
    int tid = threadIdx.x;
    int nbase = blockIdx.x * TM;

    const uint4* Wg = (const uint4*)roott;
    for (int c = tid; c < D * 16; c += 256) {
        int row = c >> 4, col = c & 15;
        *(uint4*)&sW[row * DPAD + col * 8] = Wg[c];
    }
    for (int c = tid; c < TM * 16; c += 256) {
        int row = c >> 4, col = c & 15;
        int n = nbase + row;
        if (n >= N) n = N - 1;   // clamp stays within this block's rows
        *(uint4*)&sA[row * DPAD + col * 8] = ((const uint4*)(x + (size_t)n * D))[col];
    }
    __syncthreads();

    int lane = tid & 63;
    int w = tid >> 6;
    int m = lane & 15, q = lane >> 4;
    f32x4 acc[4][2];
#pragma unroll
    for (int a = 0; a < 4; a++)
#pragma unroll
        for (int b = 0; b < 2; b++) acc[a][b] = (f32x4){0.f, 0.f, 0.f, 0.f};

#pragma unroll
    for (int k0 = 0; k0 < D; k0 += 32) {
        bf16x8 af[4], bfr[2];
#pragma unroll
        for (int mt = 0; mt < 4; mt++)
            af[mt] = *(const bf16x8*)&sA[(mt * 16 + m) * DPAD + k0 + q * 8];
#pragma unroll
        for (int nt = 0; nt < 2; nt++)
            bfr[nt] = *(const bf16x8*)&sW[(w * 32 + nt * 16 + m) * DPAD + k0 + q * 8];
#pragma unroll
        for (int mt = 0; mt < 4; mt++)
#pragma unroll
            for (int nt = 0; nt < 2; nt++)
                acc[mt][nt] = __builtin_amdgcn_mfma_f32_16x16x32_bf16(af[mt], bfr[nt], acc[mt][nt], 0, 0, 0);
    }

#pragma unroll
    for (int mt = 0; mt < 4; mt++) {
#pragma unroll
        for (int i = 0; i < 4; i++) {
            int row = mt * 16 + q * 4 + i;
            int n = nbase + row;
            if (n < N) {
#pragma unroll
                for (int nt = 0; nt < 2; nt++) {
                    int o = w * 32 + nt * 16 + m;
                    float v = acc[mt][nt][i] + agg[(size_t)n * D + o];
                    if (relu) v = fmaxf(v, 0.f);
                    if (out16) out16[(size_t)n * D + o] = (bf16_t)v;
                    else       out32[(size_t)n * D + o] = v;
                }
            }
        }
    }
}

// ---------------- host launcher ----------------

extern "C" void kernel_launch(void* const* d_in, const int* in_sizes, int n_in,
                              void* d_out, int out_size, void* d_ws, size_t ws_size,
                              hipStream_t stream) {
    const int*   entity = (const int*)d_in[0];
    const int*   ei     = (const int*)d_in[1];   // [2,E]: row0=src, row1=dst
    const int*   et     = (const int*)d_in[2];
    const float* emb    = (const float*)d_in[4];
    const float* W1     = (const float*)d_in[5];
    const float* root1  = (const float*)d_in[6];
    const float* W2     = (const float*)d_in[7];
    const float* root2  = (const float*)d_in[8];

    const int N = in_sizes[0];
    const int E = in_sizes[2];
    const int R = in_sizes[5] / (D * D);

    // carve workspace (256B-aligned chunks), total ~87 MB
    char* p = (char*)d_ws;
    auto alloc = [&](size_t bytes) -> char* {
        char* q = p; p += (bytes + 255) & ~(size_t)255; return q;
    };
    float*  agg      = (float*)alloc((size_t)N * D * 4);
    bf16_t* x        = (bf16_t*)alloc((size_t)N * D * 2);
    bf16_t* Wt       = (bf16_t*)alloc((size_t)(2 * R + 2) * D * D * 2);
    int*    s_src    = (int*)alloc((size_t)E * 4);
    int*    s_dst    = (int*)alloc((size_t)E * 4);
    int*    cnt      = (int*)alloc((size_t)(N + R) * 4);  // cnt[N] then rel_cnt[R]
    int*    rel_cnt  = cnt + N;
    float*  inv      = (float*)alloc((size_t)N * 4);
    int*    rel_off  = (int*)alloc((size_t)(R + 1) * 4);
    int*    rel_ptr  = (int*)alloc((size_t)R * 4);
    int*    tile_bs  = (int*)alloc((size_t)(R + 1) * 4);
    const int maxtiles = (E + TM - 1) / TM + R;
    int*    tile_rel = (int*)alloc((size_t)maxtiles * 4);
    int*    tile_idx = (int*)alloc((size_t)maxtiles * 4);

    // preprocessing (shared by both layers)
    hipMemsetAsync(cnt, 0, (size_t)(N + R) * 4, stream);
    deg_kernel<<<(E + 255) / 256, 256, 0, stream>>>(ei, et, E, cnt, rel_cnt, R);
    inv_kernel<<<(N + 255) / 256, 256, 0, stream>>>(cnt, inv, N);
    prefix_kernel<<<1, 256, 0, stream>>>(rel_cnt, R, rel_off, rel_ptr, tile_bs, tile_rel, tile_idx);
    scatter_kernel<<<(E + 255) / 256, 256, 0, stream>>>(ei, et, E, R, rel_ptr, s_src, s_dst);
    transpose_kernel<<<2 * R + 2, 256, 0, stream>>>(W1, root1, W2, root2, R, Wt);
    gather_kernel<<<(N * 16 + 255) / 256, 256, 0, stream>>>(entity, emb, x, N);

    // layer 1
    hipMemsetAsync(agg, 0, (size_t)N * D * 4, stream);
    edge_gemm<<<maxtiles, 256, 0, stream>>>(x, Wt, s_src, s_dst, inv,
                                            rel_off, tile_bs, tile_rel, tile_idx, R, agg);
    root_gemm<<<(N + TM - 1) / TM, 256, 0, stream>>>(x, Wt + (size_t)(2 * R) * D * D, agg,
                                                     x, (float*)nullptr, N, 1);

    // layer 2
    hipMemsetAsync(agg, 0, (size_t)N * D * 4, stream);
    edge_gemm<<<maxtiles, 256, 0, stream>>>(x, Wt + (size_t)R * D * D, s_src, s_dst, inv,
                                            rel_off, tile_bs, tile_rel, tile_idx, R, agg);
    root_gemm<<<(N + TM - 1) / TM, 256, 0, stream>>>(x, Wt + (size_t)(2 * R + 1) * D * D, agg,
                                                     (bf16_t*)nullptr, (float*)d_out, N, 0);
}

// Round 3
// 1321.462 us; speedup vs baseline: 3.0989x; 3.0989x over previous
//
#include <hip/hip_runtime.h>
#include <hip/hip_bf16.h>
#include <stdint.h>

#define D     128
#define DPAD  136   // padded LDS row stride (bf16 elems) -> 272B
#define TM    64    // rows (edges or nodes) per block tile
#define NB    256   // blocks for the histogram sort
#define RMAX  64

typedef __bf16 bf16_t;
typedef __bf16 bf16x8 __attribute__((ext_vector_type(8)));
typedef float  f32x4  __attribute__((ext_vector_type(4)));

// ---------------- preprocessing kernels ----------------

// dst in-degree (N=100K addresses, ~10 hits each: low contention)
__global__ void deg_kernel(const int* __restrict__ ei, int E, int* __restrict__ cnt) {
    int e = blockIdx.x * blockDim.x + threadIdx.x;
    if (e < E) atomicAdd(&cnt[ei[E + e]], 1);
}

__global__ void inv_kernel(const int* __restrict__ cnt, float* __restrict__ inv, int N) {
    int n = blockIdx.x * blockDim.x + threadIdx.x;
    if (n < N) inv[n] = 1.0f / (float)max(cnt[n], 1);
}

// pass 1: per-block relation histogram over a contiguous edge chunk
__global__ void hist_kernel(const int* __restrict__ et, int E, int chunk,
                            int R, int* __restrict__ blockhist) {
    __shared__ int h[RMAX];
    int tid = threadIdx.x;
    if (tid < R) h[tid] = 0;
    __syncthreads();
    int start = blockIdx.x * chunk;
    int end   = min(E, start + chunk);
    for (int i = start + tid; i < end; i += blockDim.x)
        atomicAdd(&h[et[i]], 1);
    __syncthreads();
    if (tid < R) blockhist[blockIdx.x * R + tid] = h[tid];
}

// pass 2 (1 block): column-scan blockhist -> blockoff; rel_off; tile tables
__global__ void scan_kernel(int* __restrict__ blockhist, int R,
                            int* __restrict__ blockoff,
                            int* __restrict__ rel_off, int* __restrict__ tile_base,
                            int* __restrict__ tile_rel, int* __restrict__ tile_idx) {
    __shared__ int tot[RMAX];
    __shared__ int s_off[RMAX + 1], s_tb[RMAX + 1];
    int tid = threadIdx.x;
    if (tid < R) {
        int run = 0;
        for (int b = 0; b < NB; b++) run += blockhist[b * R + tid];
        tot[tid] = run;
    }
    __syncthreads();
    if (tid == 0) {
        int acc = 0, tb = 0;
        for (int r = 0; r < R; r++) {
            s_off[r] = acc; s_tb[r] = tb;
            acc += tot[r];
            tb  += (tot[r] + TM - 1) / TM;
        }
        s_off[R] = acc; s_tb[R] = tb;
    }
    __syncthreads();
    if (tid <= R) {
        rel_off[tid]   = s_off[tid];
        tile_base[tid] = s_tb[tid];
    }
    if (tid < R) {
        int run = s_off[tid];
        for (int b = 0; b < NB; b++) {
            int v = blockhist[b * R + tid];
            blockoff[b * R + tid] = run;
            run += v;
        }
    }
    __syncthreads();
    for (int r = 0; r < R; r++) {
        int nt = s_tb[r + 1] - s_tb[r];
        for (int t = tid; t < nt; t += blockDim.x) {
            tile_rel[s_tb[r] + t] = r;
            tile_idx[s_tb[r] + t] = t;
        }
    }
}

// pass 3: deterministic-chunk scatter, position claims via private LDS counters
__global__ void scatter2_kernel(const int* __restrict__ ei, const int* __restrict__ et,
                                int E, int chunk, int R,
                                const int* __restrict__ blockoff,
                                int* __restrict__ s_src, int* __restrict__ s_dst) {
    __shared__ int ofs[RMAX];
    int tid = threadIdx.x;
    if (tid < R) ofs[tid] = blockoff[blockIdx.x * R + tid];
    __syncthreads();
    int start = blockIdx.x * chunk;
    int end   = min(E, start + chunk);
    for (int i = start + tid; i < end; i += blockDim.x) {
        int r = et[i];
        int p = atomicAdd(&ofs[r], 1);
        s_src[p] = ei[i];
        s_dst[p] = ei[E + i];
    }
}

// transpose+convert all weight matrices once: Wt[m][o][d] = (bf16)W[m][d][o]
__global__ void transpose_kernel(const float* __restrict__ W1, const float* __restrict__ root1,
                                 const float* __restrict__ W2, const float* __restrict__ root2,
                                 int R, bf16_t* __restrict__ Wt) {
    int m = blockIdx.x;  // 0..2R+1
    const float* src;
    if (m < R)            src = W1 + (size_t)m * D * D;
    else if (m < 2 * R)   src = W2 + (size_t)(m - R) * D * D;
    else if (m == 2 * R)  src = root1;
    else                  src = root2;
    bf16_t* dstp = Wt + (size_t)m * D * D;
    for (int i = threadIdx.x; i < D * D; i += blockDim.x) {
        int o = i >> 7, d = i & 127;
        dstp[i] = (bf16_t)src[d * D + o];
    }
}

// x_bf16[n][:] = (bf16)emb[entity[n]][:]  -- one thread per 8 elements
__global__ void gather_kernel(const int* __restrict__ entity, const float* __restrict__ emb,
                              bf16_t* __restrict__ x, int N) {
    int t = blockIdx.x * blockDim.x + threadIdx.x;
    if (t >= N * 16) return;
    int n = t >> 4, c = t & 15;
    const float4* src = (const float4*)(emb + (size_t)entity[n] * D) + c * 2;
    float4 a = src[0], b = src[1];
    bf16x8 v = { (bf16_t)a.x, (bf16_t)a.y, (bf16_t)a.z, (bf16_t)a.w,
                 (bf16_t)b.x, (bf16_t)b.y, (bf16_t)b.z, (bf16_t)b.w };
    *(bf16x8*)(x + (size_t)t * 8) = v;
}

// ---------------- main GEMM kernels ----------------

// per-tile: 64 edges of one relation. msg = x[src] @ W[r]; agg[dst] += msg * inv_cnt[dst]
__global__ __launch_bounds__(256, 3)
void edge_gemm(const bf16_t* __restrict__ x, const bf16_t* __restrict__ Wt,
               const int* __restrict__ s_src_g, const int* __restrict__ s_dst_g,
               const float* __restrict__ inv_cnt,
               const int* __restrict__ rel_off, const int* __restrict__ tile_base,
               const int* __restrict__ tile_rel, const int* __restrict__ tile_idx,
               int R, float* __restrict__ agg) {
    __shared__ bf16_t sW[D * DPAD];
    __shared__ bf16_t sA[TM * DPAD];
    __shared__ int   sh_src[TM];
    __shared__ int   sh_dst[TM];
    __shared__ float sh_inv[TM];

    int tile = blockIdx.x;
    if (tile >= tile_base[R]) return;
    int r = tile_rel[tile];
    int t = tile_idx[tile];
    int base = rel_off[r] + t * TM;
    int cntE = min(TM, rel_off[r + 1] - base);

    int tid = threadIdx.x;
    if (tid < TM) {
        int ok = tid < cntE;
        int s  = ok ? s_src_g[base + tid] : 0;
        int dd = ok ? s_dst_g[base + tid] : 0;
        sh_src[tid] = s;
        sh_dst[tid] = dd;
        sh_inv[tid] = ok ? inv_cnt[dd] : 0.f;
    }
    // stage W^T (L2-hot: only R distinct 32KB matrices)
    const uint4* Wg = (const uint4*)(Wt + (size_t)r * D * D);
    for (int c = tid; c < D * 16; c += 256) {
        int row = c >> 4, col = c & 15;
        *(uint4*)&sW[row * DPAD + col * 8] = Wg[c];
    }
    __syncthreads();
    // gather A rows (256B each, random from 25.6MB x)
    for (int c = tid; c < TM * 16; c += 256) {
        int row = c >> 4, col = c & 15;
        const uint4* xr = (const uint4*)(x + (size_t)sh_src[row] * D);
        *(uint4*)&sA[row * DPAD + col * 8] = xr[col];
    }
    __syncthreads();

    int lane = tid & 63;
    int w = tid >> 6;            // wave -> output cols [w*32, w*32+32)
    int m = lane & 15, q = lane >> 4;
    f32x4 acc[4][2];
#pragma unroll
    for (int a = 0; a < 4; a++)
#pragma unroll
        for (int b = 0; b < 2; b++) acc[a][b] = (f32x4){0.f, 0.f, 0.f, 0.f};

#pragma unroll
    for (int k0 = 0; k0 < D; k0 += 32) {
        bf16x8 af[4], bfr[2];
#pragma unroll
        for (int mt = 0; mt < 4; mt++)
            af[mt] = *(const bf16x8*)&sA[(mt * 16 + m) * DPAD + k0 + q * 8];
#pragma unroll
        for (int nt = 0; nt < 2; nt++)
            bfr[nt] = *(const bf16x8*)&sW[(w * 32 + nt * 16 + m) * DPAD + k0 + q * 8];
#pragma unroll
        for (int mt = 0; mt < 4; mt++)
#pragma unroll
            for (int nt = 0; nt < 2; nt++)
                acc[mt][nt] = __builtin_amdgcn_mfma_f32_16x16x32_bf16(af[mt], bfr[nt], acc[mt][nt], 0, 0, 0);
    }

    // epilogue: scale by 1/deg and atomic-accumulate (C layout: col=lane&15, row=q*4+i)
#pragma unroll
    for (int mt = 0; mt < 4; mt++) {
#pragma unroll
        for (int i = 0; i < 4; i++) {
            int edge = mt * 16 + q * 4 + i;
            if (edge < cntE) {
                float sc = sh_inv[edge];
                float* ag = agg + (size_t)sh_dst[edge] * D;
#pragma unroll
                for (int nt = 0; nt < 2; nt++) {
                    int o = w * 32 + nt * 16 + m;
                    atomicAdd(&ag[o], acc[mt][nt][i] * sc);
                }
            }
        }
    }
}

// out[n] = (relu?)( x[n] @ root + agg[n] ).  If out16 != null write bf16 (in-place
// on x is safe: each block reads only its own 64 rows before writing them),
// else write fp32 to out32.
__global__ __launch_bounds__(256, 3)
void root_gemm(const bf16_t* x, const bf16_t* __restrict__ roott,
               const float* __restrict__ agg, bf16_t* out16, float* out32,
               int N, int relu) {
    __shared__ bf16_t sW[D * DPAD];
    __shared__ bf16_t sA[TM * DPAD];
    int tid = threadIdx.x;
    int nbase = blockIdx.x * TM;

    const uint4* Wg = (const uint4*)roott;
    for (int c = tid; c < D * 16; c += 256) {
        int row = c >> 4, col = c & 15;
        *(uint4*)&sW[row * DPAD + col * 8] = Wg[c];
    }
    for (int c = tid; c < TM * 16; c += 256) {
        int row = c >> 4, col = c & 15;
        int n = nbase + row;
        if (n >= N) n = N - 1;   // clamp stays within this block's rows
        *(uint4*)&sA[row * DPAD + col * 8] = ((const uint4*)(x + (size_t)n * D))[col];
    }
    __syncthreads();

    int lane = tid & 63;
    int w = tid >> 6;
    int m = lane & 15, q = lane >> 4;
    f32x4 acc[4][2];
#pragma unroll
    for (int a = 0; a < 4; a++)
#pragma unroll
        for (int b = 0; b < 2; b++) acc[a][b] = (f32x4){0.f, 0.f, 0.f, 0.f};

#pragma unroll
    for (int k0 = 0; k0 < D; k0 += 32) {
        bf16x8 af[4], bfr[2];
#pragma unroll
        for (int mt = 0; mt < 4; mt++)
            af[mt] = *(const bf16x8*)&sA[(mt * 16 + m) * DPAD + k0 + q * 8];
#pragma unroll
        for (int nt = 0; nt < 2; nt++)
            bfr[nt] = *(const bf16x8*)&sW[(w * 32 + nt * 16 + m) * DPAD + k0 + q * 8];
#pragma unroll
        for (int mt = 0; mt < 4; mt++)
#pragma unroll
            for (int nt = 0; nt < 2; nt++)
                acc[mt][nt] = __builtin_amdgcn_mfma_f32_16x16x32_bf16(af[mt], bfr[nt], acc[mt][nt], 0, 0, 0);
    }

#pragma unroll
    for (int mt = 0; mt < 4; mt++) {
#pragma unroll
        for (int i = 0; i < 4; i++) {
            int row = mt * 16 + q * 4 + i;
            int n = nbase + row;
            if (n < N) {
#pragma unroll
                for (int nt = 0; nt < 2; nt++) {
                    int o = w * 32 + nt * 16 + m;
                    float v = acc[mt][nt][i] + agg[(size_t)n * D + o];
                    if (relu) v = fmaxf(v, 0.f);
                    if (out16) out16[(size_t)n * D + o] = (bf16_t)v;
                    else       out32[(size_t)n * D + o] = v;
                }
            }
        }
    }
}

// ---------------- host launcher ----------------

extern "C" void kernel_launch(void* const* d_in, const int* in_sizes, int n_in,
                              void* d_out, int out_size, void* d_ws, size_t ws_size,
                              hipStream_t stream) {
    const int*   entity = (const int*)d_in[0];
    const int*   ei     = (const int*)d_in[1];   // [2,E]: row0=src, row1=dst
    const int*   et     = (const int*)d_in[2];
    const float* emb    = (const float*)d_in[4];
    const float* W1     = (const float*)d_in[5];
    const float* root1  = (const float*)d_in[6];
    const float* W2     = (const float*)d_in[7];
    const float* root2  = (const float*)d_in[8];

    const int N = in_sizes[0];
    const int E = in_sizes[2];
    const int R = in_sizes[5] / (D * D);

    // carve workspace (256B-aligned chunks), total ~87 MB
    char* p = (char*)d_ws;
    auto alloc = [&](size_t bytes) -> char* {
        char* q = p; p += (bytes + 255) & ~(size_t)255; return q;
    };
    float*  agg      = (float*)alloc((size_t)N * D * 4);
    bf16_t* x        = (bf16_t*)alloc((size_t)N * D * 2);
    bf16_t* Wt       = (bf16_t*)alloc((size_t)(2 * R + 2) * D * D * 2);
    int*    s_src    = (int*)alloc((size_t)E * 4);
    int*    s_dst    = (int*)alloc((size_t)E * 4);
    int*    cnt      = (int*)alloc((size_t)N * 4);
    float*  inv      = (float*)alloc((size_t)N * 4);
    int*    blockhist= (int*)alloc((size_t)NB * R * 4);
    int*    blockoff = (int*)alloc((size_t)NB * R * 4);
    int*    rel_off  = (int*)alloc((size_t)(R + 1) * 4);
    int*    tile_bs  = (int*)alloc((size_t)(R + 1) * 4);
    const int maxtiles = (E + TM - 1) / TM + R;
    int*    tile_rel = (int*)alloc((size_t)maxtiles * 4);
    int*    tile_idx = (int*)alloc((size_t)maxtiles * 4);

    const int chunk = (E + NB - 1) / NB;

    // preprocessing (shared by both layers)
    hipMemsetAsync(cnt, 0, (size_t)N * 4, stream);
    deg_kernel<<<(E + 255) / 256, 256, 0, stream>>>(ei, E, cnt);
    inv_kernel<<<(N + 255) / 256, 256, 0, stream>>>(cnt, inv, N);
    hist_kernel<<<NB, 256, 0, stream>>>(et, E, chunk, R, blockhist);
    scan_kernel<<<1, 256, 0, stream>>>(blockhist, R, blockoff, rel_off, tile_bs, tile_rel, tile_idx);
    scatter2_kernel<<<NB, 256, 0, stream>>>(ei, et, E, chunk, R, blockoff, s_src, s_dst);
    transpose_kernel<<<2 * R + 2, 256, 0, stream>>>(W1, root1, W2, root2, R, Wt);
    gather_kernel<<<(N * 16 + 255) / 256, 256, 0, stream>>>(entity, emb, x, N);

    // layer 1
    hipMemsetAsync(agg, 0, (size_t)N * D * 4, stream);
    edge_gemm<<<maxtiles, 256, 0, stream>>>(x, Wt, s_src, s_dst, inv,
                                            rel_off, tile_bs, tile_rel, tile_idx, R, agg);
    root_gemm<<<(N + TM - 1) / TM, 256, 0, stream>>>(x, Wt + (size_t)(2 * R) * D * D, agg,
                                                     x, (float*)nullptr, N, 1);

    // layer 2
    hipMemsetAsync(agg, 0, (size_t)N * D * 4, stream);
    edge_gemm<<<maxtiles, 256, 0, stream>>>(x, Wt + (size_t)R * D * D, s_src, s_dst, inv,
                                            rel_off, tile_bs, tile_rel, tile_idx, R, agg);
    root_gemm<<<(N + TM - 1) / TM, 256, 0, stream>>>(x, Wt + (size_t)(2 * R + 1) * D * D, agg,
                                                     (bf16_t*)nullptr, (float*)d_out, N, 0);
}

// Round 4
// 1166.153 us; speedup vs baseline: 3.5117x; 1.1332x over previous
//
#include <hip/hip_runtime.h>
#include <hip/hip_bf16.h>
#include <stdint.h>

#define D     128
#define DPAD  136   // padded LDS row stride (bf16 elems) -> 272B
#define TM    64    // rows (edges or nodes) per block tile
#define NB    256   // blocks for the histogram sort
#define RMAX  64
#define SCAN_T 1024

typedef __bf16 bf16_t;
typedef __bf16 bf16x8 __attribute__((ext_vector_type(8)));
typedef float  f32x4  __attribute__((ext_vector_type(4)));

// ---------------- preprocessing kernels ----------------

// dst in-degree (N=100K addresses, ~10 hits each: low contention)
__global__ void deg_kernel(const int* __restrict__ ei, int E, int* __restrict__ cnt) {
    int e = blockIdx.x * blockDim.x + threadIdx.x;
    if (e < E) atomicAdd(&cnt[ei[E + e]], 1);
}

__global__ void inv_kernel(const int* __restrict__ cnt, float* __restrict__ inv, int N) {
    int n = blockIdx.x * blockDim.x + threadIdx.x;
    if (n < N) inv[n] = 1.0f / (float)max(cnt[n], 1);
}

// pass 1: per-block relation histogram over a contiguous edge chunk
__global__ void hist_kernel(const int* __restrict__ et, int E, int chunk,
                            int R, int* __restrict__ blockhist) {
    __shared__ int h[RMAX];
    int tid = threadIdx.x;
    if (tid < R) h[tid] = 0;
    __syncthreads();
    int start = blockIdx.x * chunk;
    int end   = min(E, start + chunk);
    for (int i = start + tid; i < end; i += blockDim.x)
        atomicAdd(&h[et[i]], 1);
    __syncthreads();
    if (tid < R) blockhist[blockIdx.x * R + tid] = h[tid];
}

// pass 2 (1 block): column-scan blockhist -> blockoff; rel_off; tile tables
__global__ void scan_kernel(int* __restrict__ blockhist, int R,
                            int* __restrict__ blockoff,
                            int* __restrict__ rel_off, int* __restrict__ tile_base,
                            int* __restrict__ tile_rel, int* __restrict__ tile_idx) {
    __shared__ int tot[RMAX];
    __shared__ int s_off[RMAX + 1], s_tb[RMAX + 1];
    int tid = threadIdx.x;
    if (tid < R) {
        int run = 0;
        for (int b = 0; b < NB; b++) run += blockhist[b * R + tid];
        tot[tid] = run;
    }
    __syncthreads();
    if (tid == 0) {
        int acc = 0, tb = 0;
        for (int r = 0; r < R; r++) {
            s_off[r] = acc; s_tb[r] = tb;
            acc += tot[r];
            tb  += (tot[r] + TM - 1) / TM;
        }
        s_off[R] = acc; s_tb[R] = tb;
    }
    __syncthreads();
    if (tid <= R) {
        rel_off[tid]   = s_off[tid];
        tile_base[tid] = s_tb[tid];
    }
    if (tid < R) {
        int run = s_off[tid];
        for (int b = 0; b < NB; b++) {
            int v = blockhist[b * R + tid];
            blockoff[b * R + tid] = run;
            run += v;
        }
    }
    __syncthreads();
    for (int r = 0; r < R; r++) {
        int nt = s_tb[r + 1] - s_tb[r];
        for (int t = tid; t < nt; t += blockDim.x) {
            tile_rel[s_tb[r] + t] = r;
            tile_idx[s_tb[r] + t] = t;
        }
    }
}

// pass 3: deterministic-chunk scatter, position claims via private LDS counters.
// Optionally records dst per slot (atomic fallback) and original edge id (scatter path).
__global__ void scatter2_kernel(const int* __restrict__ ei, const int* __restrict__ et,
                                int E, int chunk, int R,
                                const int* __restrict__ blockoff,
                                int* __restrict__ s_src, int* s_dst, int* s_eid) {
    __shared__ int ofs[RMAX];
    int tid = threadIdx.x;
    if (tid < R) ofs[tid] = blockoff[blockIdx.x * R + tid];
    __syncthreads();
    int start = blockIdx.x * chunk;
    int end   = min(E, start + chunk);
    for (int i = start + tid; i < end; i += blockDim.x) {
        int r = et[i];
        int p = atomicAdd(&ofs[r], 1);
        s_src[p] = ei[i];
        if (s_dst) s_dst[p] = ei[E + i];
        if (s_eid) s_eid[p] = i;
    }
}

// 1-block exclusive prefix sum over cnt[N] -> dst_off[N+1]; dst_ptr = copy
__global__ void scanN_kernel(const int* __restrict__ cnt, int N,
                             int* __restrict__ dst_off, int* __restrict__ dst_ptr) {
    __shared__ int ts[SCAN_T];
    int tid = threadIdx.x;
    int chunk = (N + SCAN_T - 1) / SCAN_T;
    int s = tid * chunk, e = min(N, s + chunk);
    int sum = 0;
    for (int i = s; i < e; i++) sum += cnt[i];
    ts[tid] = sum;
    __syncthreads();
    for (int off = 1; off < SCAN_T; off <<= 1) {
        int v = (tid >= off) ? ts[tid - off] : 0;
        __syncthreads();
        ts[tid] += v;
        __syncthreads();
    }
    int run = (tid == 0) ? 0 : ts[tid - 1];   // exclusive base for this chunk
    for (int i = s; i < e; i++) {
        dst_off[i] = run;
        dst_ptr[i] = run;
        run += cnt[i];
    }
    if (tid == SCAN_T - 1) dst_off[N] = run;
}

// each original edge claims its dst-sorted slot (contention ~avg-degree: fine)
__global__ void dstclaim_kernel(const int* __restrict__ ei, int E,
                                int* __restrict__ dst_ptr, int* __restrict__ dstpos) {
    int i = blockIdx.x * blockDim.x + threadIdx.x;
    if (i < E) dstpos[i] = atomicAdd(&dst_ptr[ei[E + i]], 1);
}

// msgpos[rel-sorted position] = dst-sorted slot
__global__ void map_kernel(const int* __restrict__ s_eid, const int* __restrict__ dstpos,
                           int E, int* __restrict__ msgpos) {
    int p = blockIdx.x * blockDim.x + threadIdx.x;
    if (p < E) msgpos[p] = dstpos[s_eid[p]];
}

// transpose+convert all weight matrices once: Wt[m][o][d] = (bf16)W[m][d][o]
__global__ void transpose_kernel(const float* __restrict__ W1, const float* __restrict__ root1,
                                 const float* __restrict__ W2, const float* __restrict__ root2,
                                 int R, bf16_t* __restrict__ Wt) {
    int m = blockIdx.x;  // 0..2R+1
    const float* src;
    if (m < R)            src = W1 + (size_t)m * D * D;
    else if (m < 2 * R)   src = W2 + (size_t)(m - R) * D * D;
    else if (m == 2 * R)  src = root1;
    else                  src = root2;
    bf16_t* dstp = Wt + (size_t)m * D * D;
    for (int i = threadIdx.x; i < D * D; i += blockDim.x) {
        int o = i >> 7, d = i & 127;
        dstp[i] = (bf16_t)src[d * D + o];
    }
}

// x_bf16[n][:] = (bf16)emb[entity[n]][:]
__global__ void gather_kernel(const int* __restrict__ entity, const float* __restrict__ emb,
                              bf16_t* __restrict__ x, int N) {
    int t = blockIdx.x * blockDim.x + threadIdx.x;
    if (t >= N * 16) return;
    int n = t >> 4, c = t & 15;
    const float4* src = (const float4*)(emb + (size_t)entity[n] * D) + c * 2;
    float4 a = src[0], b = src[1];
    bf16x8 v = { (bf16_t)a.x, (bf16_t)a.y, (bf16_t)a.z, (bf16_t)a.w,
                 (bf16_t)b.x, (bf16_t)b.y, (bf16_t)b.z, (bf16_t)b.w };
    *(bf16x8*)(x + (size_t)t * 8) = v;
}

// ---------------- main GEMM kernels ----------------

// scatter variant: msg = x[src] @ W[r], streamed as bf16 rows to msgs[slot] (no atomics)
__global__ __launch_bounds__(256, 3)
void edge_gemm_scatter(const bf16_t* __restrict__ x, const bf16_t* __restrict__ Wt,
                       const int* __restrict__ s_src_g, const int* __restrict__ msgpos,
                       const int* __restrict__ rel_off, const int* __restrict__ tile_base,
                       const int* __restrict__ tile_rel, const int* __restrict__ tile_idx,
                       int R, bf16_t* __restrict__ msgs) {
    __shared__ bf16_t sW[D * DPAD];
    __shared__ bf16_t sA[TM * DPAD];
    __shared__ int   sh_src[TM];
    __shared__ int   sh_slot[TM];

    int tile = blockIdx.x;
    if (tile >= tile_base[R]) return;
    int r = tile_rel[tile];
    int t = tile_idx[tile];
    int base = rel_off[r] + t * TM;
    int cntE = min(TM, rel_off[r + 1] - base);

    int tid = threadIdx.x;
    if (tid < TM) {
        int ok = tid < cntE;
        sh_src[tid]  = ok ? s_src_g[base + tid] : 0;
        sh_slot[tid] = ok ? msgpos[base + tid] : 0;
    }
    const uint4* Wg = (const uint4*)(Wt + (size_t)r * D * D);
    for (int c = tid; c < D * 16; c += 256) {
        int row = c >> 4, col = c & 15;
        *(uint4*)&sW[row * DPAD + col * 8] = Wg[c];
    }
    __syncthreads();
    for (int c = tid; c < TM * 16; c += 256) {
        int row = c >> 4, col = c & 15;
        const uint4* xr = (const uint4*)(x + (size_t)sh_src[row] * D);
        *(uint4*)&sA[row * DPAD + col * 8] = xr[col];
    }
    __syncthreads();

    int lane = tid & 63;
    int w = tid >> 6;
    int m = lane & 15, q = lane >> 4;
    f32x4 acc[4][2];
#pragma unroll
    for (int a = 0; a < 4; a++)
#pragma unroll
        for (int b = 0; b < 2; b++) acc[a][b] = (f32x4){0.f, 0.f, 0.f, 0.f};

#pragma unroll
    for (int k0 = 0; k0 < D; k0 += 32) {
        bf16x8 af[4], bfr[2];
#pragma unroll
        for (int mt = 0; mt < 4; mt++)
            af[mt] = *(const bf16x8*)&sA[(mt * 16 + m) * DPAD + k0 + q * 8];
#pragma unroll
        for (int nt = 0; nt < 2; nt++)
            bfr[nt] = *(const bf16x8*)&sW[(w * 32 + nt * 16 + m) * DPAD + k0 + q * 8];
#pragma unroll
        for (int mt = 0; mt < 4; mt++)
#pragma unroll
            for (int nt = 0; nt < 2; nt++)
                acc[mt][nt] = __builtin_amdgcn_mfma_f32_16x16x32_bf16(af[mt], bfr[nt], acc[mt][nt], 0, 0, 0);
    }

    // epilogue: repack acc -> row-major bf16 in LDS (reuse sA), stream rows out
    __syncthreads();
#pragma unroll
    for (int mt = 0; mt < 4; mt++)
#pragma unroll
        for (int i = 0; i < 4; i++) {
            int row = mt * 16 + q * 4 + i;
#pragma unroll
            for (int nt = 0; nt < 2; nt++)
                sA[row * DPAD + w * 32 + nt * 16 + m] = (bf16_t)acc[mt][nt][i];
        }
    __syncthreads();
    for (int c = tid; c < cntE * 16; c += 256) {
        int row = c >> 4, col = c & 15;
        ((uint4*)msgs)[(size_t)sh_slot[row] * 16 + col] = *(uint4*)&sA[row * DPAD + col * 8];
    }
}

// atomic fallback (round-3 path, used only if workspace too small for msgs)
__global__ __launch_bounds__(256, 3)
void edge_gemm_atomic(const bf16_t* __restrict__ x, const bf16_t* __restrict__ Wt,
                      const int* __restrict__ s_src_g, const int* __restrict__ s_dst_g,
                      const float* __restrict__ inv_cnt,
                      const int* __restrict__ rel_off, const int* __restrict__ tile_base,
                      const int* __restrict__ tile_rel, const int* __restrict__ tile_idx,
                      int R, float* __restrict__ agg) {
    __shared__ bf16_t sW[D * DPAD];
    __shared__ bf16_t sA[TM * DPAD];
    __shared__ int   sh_src[TM];
    __shared__ int   sh_dst[TM];
    __shared__ float sh_inv[TM];

    int tile = blockIdx.x;
    if (tile >= tile_base[R]) return;
    int r = tile_rel[tile];
    int t = tile_idx[tile];
    int base = rel_off[r] + t * TM;
    int cntE = min(TM, rel_off[r + 1] - base);

    int tid = threadIdx.x;
    if (tid < TM) {
        int ok = tid < cntE;
        int s  = ok ? s_src_g[base + tid] : 0;
        int dd = ok ? s_dst_g[base + tid] : 0;
        sh_src[tid] = s;
        sh_dst[tid] = dd;
        sh_inv[tid] = ok ? inv_cnt[dd] : 0.f;
    }
    const uint4* Wg = (const uint4*)(Wt + (size_t)r * D * D);
    for (int c = tid; c < D * 16; c += 256) {
        int row = c >> 4, col = c & 15;
        *(uint4*)&sW[row * DPAD + col * 8] = Wg[c];
    }
    __syncthreads();
    for (int c = tid; c < TM * 16; c += 256) {
        int row = c >> 4, col = c & 15;
        const uint4* xr = (const uint4*)(x + (size_t)sh_src[row] * D);
        *(uint4*)&sA[row * DPAD + col * 8] = xr[col];
    }
    __syncthreads();

    int lane = tid & 63;
    int w = tid >> 6;
    int m = lane & 15, q = lane >> 4;
    f32x4 acc[4][2];
#pragma unroll
    for (int a = 0; a < 4; a++)
#pragma unroll
        for (int b = 0; b < 2; b++) acc[a][b] = (f32x4){0.f, 0.f, 0.f, 0.f};

#pragma unroll
    for (int k0 = 0; k0 < D; k0 += 32) {
        bf16x8 af[4], bfr[2];
#pragma unroll
        for (int mt = 0; mt < 4; mt++)
            af[mt] = *(const bf16x8*)&sA[(mt * 16 + m) * DPAD + k0 + q * 8];
#pragma unroll
        for (int nt = 0; nt < 2; nt++)
            bfr[nt] = *(const bf16x8*)&sW[(w * 32 + nt * 16 + m) * DPAD + k0 + q * 8];
#pragma unroll
        for (int mt = 0; mt < 4; mt++)
#pragma unroll
            for (int nt = 0; nt < 2; nt++)
                acc[mt][nt] = __builtin_amdgcn_mfma_f32_16x16x32_bf16(af[mt], bfr[nt], acc[mt][nt], 0, 0, 0);
    }

#pragma unroll
    for (int mt = 0; mt < 4; mt++)
#pragma unroll
        for (int i = 0; i < 4; i++) {
            int edge = mt * 16 + q * 4 + i;
            if (edge < cntE) {
                float sc = sh_inv[edge];
                float* ag = agg + (size_t)sh_dst[edge] * D;
#pragma unroll
                for (int nt = 0; nt < 2; nt++) {
                    int o = w * 32 + nt * 16 + m;
                    atomicAdd(&ag[o], acc[mt][nt][i] * sc);
                }
            }
        }
}

// coalesced segmented sum: agg[n] = inv[n] * sum of msgs rows [dst_off[n], dst_off[n+1])
__global__ __launch_bounds__(256)
void seg_sum(const bf16_t* __restrict__ msgs, const int* __restrict__ dst_off,
             const float* __restrict__ inv, float* __restrict__ agg, int N) {
    int node = blockIdx.x * 16 + (threadIdx.x >> 4);
    int t = threadIdx.x & 15;
    if (node >= N) return;
    int s = dst_off[node], e = dst_off[node + 1];
    float sum[8] = {0.f, 0.f, 0.f, 0.f, 0.f, 0.f, 0.f, 0.f};
    for (int j = s; j < e; j++) {
        bf16x8 v = *(const bf16x8*)(msgs + (size_t)j * D + t * 8);
#pragma unroll
        for (int k = 0; k < 8; k++) sum[k] += (float)v[k];
    }
    float sc = inv[node];
    float* out = agg + (size_t)node * D + t * 8;
    *(float4*)out       = (float4){sum[0] * sc, sum[1] * sc, sum[2] * sc, sum[3] * sc};
    *(float4*)(out + 4) = (float4){sum[4] * sc, sum[5] * sc, sum[6] * sc, sum[7] * sc};
}

// out[n] = (relu?)( x[n] @ root + agg[n] )
__global__ __launch_bounds__(256, 3)
void root_gemm(const bf16_t* x, const bf16_t* __restrict__ roott,
               const float* __restrict__ agg, bf16_t* out16, float* out32,
               int N, int relu) {
    __shared__ bf16_t sW[D * DPAD];
    __shared__ bf16_t sA[TM * DPAD];
    int tid = threadIdx.x;
    int nbase = blockIdx.x * TM;

    const uint4* Wg = (const uint4*)roott;
    for (int c = tid; c < D * 16; c += 256) {
        int row = c >> 4, col = c & 15;
        *(uint4*)&sW[row * DPAD + col * 8] = Wg[c];
    }
    for (int c = tid; c < TM * 16; c += 256) {
        int row = c >> 4, col = c & 15;
        int n = nbase + row;
        if (n >= N) n = N - 1;
        *(uint4*)&sA[row * DPAD + col * 8] = ((const uint4*)(x + (size_t)n * D))[col];
    }
    __syncthreads();

    int lane = tid & 63;
    int w = tid >> 6;
    int m = lane & 15, q = lane >> 4;
    f32x4 acc[4][2];
#pragma unroll
    for (int a = 0; a < 4; a++)
#pragma unroll
        for (int b = 0; b < 2; b++) acc[a][b] = (f32x4){0.f, 0.f, 0.f, 0.f};

#pragma unroll
    for (int k0 = 0; k0 < D; k0 += 32) {
        bf16x8 af[4], bfr[2];
#pragma unroll
        for (int mt = 0; mt < 4; mt++)
            af[mt] = *(const bf16x8*)&sA[(mt * 16 + m) * DPAD + k0 + q * 8];
#pragma unroll
        for (int nt = 0; nt < 2; nt++)
            bfr[nt] = *(const bf16x8*)&sW[(w * 32 + nt * 16 + m) * DPAD + k0 + q * 8];
#pragma unroll
        for (int mt = 0; mt < 4; mt++)
#pragma unroll
            for (int nt = 0; nt < 2; nt++)
                acc[mt][nt] = __builtin_amdgcn_mfma_f32_16x16x32_bf16(af[mt], bfr[nt], acc[mt][nt], 0, 0, 0);
    }

#pragma unroll
    for (int mt = 0; mt < 4; mt++)
#pragma unroll
        for (int i = 0; i < 4; i++) {
            int row = mt * 16 + q * 4 + i;
            int n = nbase + row;
            if (n < N) {
#pragma unroll
                for (int nt = 0; nt < 2; nt++) {
                    int o = w * 32 + nt * 16 + m;
                    float v = acc[mt][nt][i] + agg[(size_t)n * D + o];
                    if (relu) v = fmaxf(v, 0.f);
                    if (out16) out16[(size_t)n * D + o] = (bf16_t)v;
                    else       out32[(size_t)n * D + o] = v;
                }
            }
        }
}

// ---------------- host launcher ----------------

extern "C" void kernel_launch(void* const* d_in, const int* in_sizes, int n_in,
                              void* d_out, int out_size, void* d_ws, size_t ws_size,
                              hipStream_t stream) {
    const int*   entity = (const int*)d_in[0];
    const int*   ei     = (const int*)d_in[1];   // [2,E]: row0=src, row1=dst
    const int*   et     = (const int*)d_in[2];
    const float* emb    = (const float*)d_in[4];
    const float* W1     = (const float*)d_in[5];
    const float* root1  = (const float*)d_in[6];
    const float* W2     = (const float*)d_in[7];
    const float* root2  = (const float*)d_in[8];

    const int N = in_sizes[0];
    const int E = in_sizes[2];
    const int R = in_sizes[5] / (D * D);

    char* p = (char*)d_ws;
    auto alloc = [&](size_t bytes) -> char* {
        char* q = p; p += (bytes + 255) & ~(size_t)255; return q;
    };
    // common region
    float*  agg      = (float*)alloc((size_t)N * D * 4);
    bf16_t* x        = (bf16_t*)alloc((size_t)N * D * 2);
    bf16_t* Wt       = (bf16_t*)alloc((size_t)(2 * R + 2) * D * D * 2);
    int*    s_src    = (int*)alloc((size_t)E * 4);
    int*    cnt      = (int*)alloc((size_t)N * 4);
    float*  inv      = (float*)alloc((size_t)N * 4);
    int*    blockhist= (int*)alloc((size_t)NB * R * 4);
    int*    blockoff = (int*)alloc((size_t)NB * R * 4);
    int*    rel_off  = (int*)alloc((size_t)(R + 1) * 4);
    int*    tile_bs  = (int*)alloc((size_t)(R + 1) * 4);
    const int maxtiles = (E + TM - 1) / TM + R;
    int*    tile_rel = (int*)alloc((size_t)maxtiles * 4);
    int*    tile_idx = (int*)alloc((size_t)maxtiles * 4);
    char*   p_common = p;

    // scatter-path extras
    bf16_t* msgs    = (bf16_t*)alloc((size_t)E * D * 2);
    int*    s_eid   = (int*)alloc((size_t)E * 4);
    int*    msgpos  = (int*)alloc((size_t)E * 4);
    int*    dstpos  = (int*)alloc((size_t)E * 4);
    int*    dst_off = (int*)alloc((size_t)(N + 1) * 4);
    int*    dst_ptr = (int*)alloc((size_t)N * 4);
    bool big = ((size_t)(p - (char*)d_ws) <= ws_size);

    int* s_dst = nullptr;
    if (!big) { p = p_common; s_dst = (int*)alloc((size_t)E * 4); }

    const int chunk = (E + NB - 1) / NB;

    // shared preprocessing
    hipMemsetAsync(cnt, 0, (size_t)N * 4, stream);
    deg_kernel<<<(E + 255) / 256, 256, 0, stream>>>(ei, E, cnt);
    inv_kernel<<<(N + 255) / 256, 256, 0, stream>>>(cnt, inv, N);
    hist_kernel<<<NB, 256, 0, stream>>>(et, E, chunk, R, blockhist);
    scan_kernel<<<1, 256, 0, stream>>>(blockhist, R, blockoff, rel_off, tile_bs, tile_rel, tile_idx);
    scatter2_kernel<<<NB, 256, 0, stream>>>(ei, et, E, chunk, R, blockoff,
                                            s_src, big ? nullptr : s_dst, big ? s_eid : nullptr);
    transpose_kernel<<<2 * R + 2, 256, 0, stream>>>(W1, root1, W2, root2, R, Wt);
    gather_kernel<<<(N * 16 + 255) / 256, 256, 0, stream>>>(entity, emb, x, N);

    if (big) {
        scanN_kernel<<<1, SCAN_T, 0, stream>>>(cnt, N, dst_off, dst_ptr);
        dstclaim_kernel<<<(E + 255) / 256, 256, 0, stream>>>(ei, E, dst_ptr, dstpos);
        map_kernel<<<(E + 255) / 256, 256, 0, stream>>>(s_eid, dstpos, E, msgpos);

        // layer 1
        edge_gemm_scatter<<<maxtiles, 256, 0, stream>>>(x, Wt, s_src, msgpos,
                                                        rel_off, tile_bs, tile_rel, tile_idx, R, msgs);
        seg_sum<<<(N + 15) / 16, 256, 0, stream>>>(msgs, dst_off, inv, agg, N);
        root_gemm<<<(N + TM - 1) / TM, 256, 0, stream>>>(x, Wt + (size_t)(2 * R) * D * D, agg,
                                                         x, (float*)nullptr, N, 1);
        // layer 2
        edge_gemm_scatter<<<maxtiles, 256, 0, stream>>>(x, Wt + (size_t)R * D * D, s_src, msgpos,
                                                        rel_off, tile_bs, tile_rel, tile_idx, R, msgs);
        seg_sum<<<(N + 15) / 16, 256, 0, stream>>>(msgs, dst_off, inv, agg, N);
        root_gemm<<<(N + TM - 1) / TM, 256, 0, stream>>>(x, Wt + (size_t)(2 * R + 1) * D * D, agg,
                                                         (bf16_t*)nullptr, (float*)d_out, N, 0);
    } else {
        // atomic fallback (round-3 structure)
        hipMemsetAsync(agg, 0, (size_t)N * D * 4, stream);
        edge_gemm_atomic<<<maxtiles, 256, 0, stream>>>(x, Wt, s_src, s_dst, inv,
                                                       rel_off, tile_bs, tile_rel, tile_idx, R, agg);
        root_gemm<<<(N + TM - 1) / TM, 256, 0, stream>>>(x, Wt + (size_t)(2 * R) * D * D, agg,
                                                         x, (float*)nullptr, N, 1);
        hipMemsetAsync(agg, 0, (size_t)N * D * 4, stream);
        edge_gemm_atomic<<<maxtiles, 256, 0, stream>>>(x, Wt + (size_t)R * D * D, s_src, s_dst, inv,
                                                       rel_off, tile_bs, tile_rel, tile_idx, R, agg);
        root_gemm<<<(N + TM - 1) / TM, 256, 0, stream>>>(x, Wt + (size_t)(2 * R + 1) * D * D, agg,
                                                         (bf16_t*)nullptr, (float*)d_out, N, 0);
    }
}